// Round 1
// baseline (38.863 us; speedup 1.0000x reference)
//
#include <hip/hip_runtime.h>

// Problem geometry (fixed by reference): N=32, C=255, H=W=80, A=3, V=85
constexpr int HW      = 80 * 80;          // 6400 floats per channel plane
constexpr int NPLANE  = 32 * 3;           // N*A = 96 (n,a) planes
constexpr int NV      = 85;               // values per anchor (2 xy, 2 wh, obj, 80 cls)
constexpr int QCELLS  = NPLANE * HW / 4;  // threads, 4 cells each = 153600
constexpr int BOX_ELEMS = NPLANE * HW * 6; // 3,686,400 floats of boxes output

__device__ __forceinline__ float sigmoidf_(float v) {
    return 1.0f / (1.0f + __expf(-v));
}

__global__ __launch_bounds__(256)
void box_decode_kernel(const float* __restrict__ x,
                       const float* __restrict__ anchors,
                       float* __restrict__ out) {
    const int idx4 = blockIdx.x * 256 + threadIdx.x;
    if (idx4 >= QCELLS) return;

    const int plane = idx4 / (HW / 4);          // (n*3 + a)
    const int rem   = idx4 - plane * (HW / 4);  // quarter-cell within plane
    const int a     = plane % 3;

    // Within a plane, rem*4 == h*80 + w (w multiple of 4): contiguous addressing.
    const float* base = x + (size_t)plane * (NV * HW) + rem * 4;

    const float4 tx  = *(const float4*)(base + 0 * HW);
    const float4 ty  = *(const float4*)(base + 1 * HW);
    const float4 tw  = *(const float4*)(base + 2 * HW);
    const float4 th  = *(const float4*)(base + 3 * HW);
    const float4 obj = *(const float4*)(base + 4 * HW);

    // class 0 initializes the running max (first-occurrence tie-break preserved
    // by strict > updates below, matching jnp.argmax)
    float4 best = *(const float4*)(base + 5 * HW);
    best.x *= obj.x; best.y *= obj.y; best.z *= obj.z; best.w *= obj.w;
    float4 bcls = {0.f, 0.f, 0.f, 0.f};

#pragma unroll 4
    for (int v = 6; v < NV; ++v) {
        float4 s = *(const float4*)(base + v * HW);
        s.x *= obj.x; s.y *= obj.y; s.z *= obj.z; s.w *= obj.w;
        const float c = (float)(v - 5);
        if (s.x > best.x) { best.x = s.x; bcls.x = c; }
        if (s.y > best.y) { best.y = s.y; bcls.y = c; }
        if (s.z > best.z) { best.z = s.z; bcls.z = c; }
        if (s.w > best.w) { best.w = s.w; bcls.w = c; }
    }

    const int h  = rem / 20;        // 20 quarter-groups per row of 80
    const int w0 = (rem % 20) * 4;

    const float ax = anchors[2 * a + 0];
    const float ay = anchors[2 * a + 1];

    float bx[4], by[4], bw[4], bh[4];
    bx[0] = sigmoidf_(tx.x) + (float)(w0 + 0);
    bx[1] = sigmoidf_(tx.y) + (float)(w0 + 1);
    bx[2] = sigmoidf_(tx.z) + (float)(w0 + 2);
    bx[3] = sigmoidf_(tx.w) + (float)(w0 + 3);
    const float hf = (float)h;
    by[0] = sigmoidf_(ty.x) + hf;
    by[1] = sigmoidf_(ty.y) + hf;
    by[2] = sigmoidf_(ty.z) + hf;
    by[3] = sigmoidf_(ty.w) + hf;
    bw[0] = __expf(tw.x) * ax; bw[1] = __expf(tw.y) * ax;
    bw[2] = __expf(tw.z) * ax; bw[3] = __expf(tw.w) * ax;
    bh[0] = __expf(th.x) * ay; bh[1] = __expf(th.y) * ay;
    bh[2] = __expf(th.z) * ay; bh[3] = __expf(th.w) * ay;

    const float bs[4]  = {best.x, best.y, best.z, best.w};
    const float bcl[4] = {bcls.x, bcls.y, bcls.z, bcls.w};

    // 24 contiguous floats (4 cells x 6 attrs) -> 6 aligned float4 stores.
    float vals[24];
#pragma unroll
    for (int j = 0; j < 4; ++j) {
        vals[j * 6 + 0] = bx[j];
        vals[j * 6 + 1] = by[j];
        vals[j * 6 + 2] = bw[j];
        vals[j * 6 + 3] = bh[j];
        vals[j * 6 + 4] = bs[j];
        vals[j * 6 + 5] = bcl[j];
    }
    float* op = out + (size_t)idx4 * 24;   // 96-byte aligned
#pragma unroll
    for (int j = 0; j < 6; ++j) {
        *(float4*)(op + j * 4) = *(const float4*)(vals + j * 4);
    }

    // mask output (float 1.0/0.0), contiguous after boxes
    float4 m;
    m.x = bs[0] > 0.5f ? 1.0f : 0.0f;
    m.y = bs[1] > 0.5f ? 1.0f : 0.0f;
    m.z = bs[2] > 0.5f ? 1.0f : 0.0f;
    m.w = bs[3] > 0.5f ? 1.0f : 0.0f;
    *(float4*)(out + BOX_ELEMS + (size_t)idx4 * 4) = m;
}

extern "C" void kernel_launch(void* const* d_in, const int* in_sizes, int n_in,
                              void* d_out, int out_size, void* d_ws, size_t ws_size,
                              hipStream_t stream) {
    const float* x       = (const float*)d_in[0];
    const float* anchors = (const float*)d_in[1];
    float* out           = (float*)d_out;

    const int nthreads = QCELLS;               // 153600
    const int nblocks  = (nthreads + 255) / 256; // 600
    box_decode_kernel<<<nblocks, 256, 0, stream>>>(x, anchors, out);
}